// Round 4
// baseline (164.943 us; speedup 1.0000x reference)
//
#include <hip/hip_runtime.h>
#include <hip/hip_bf16.h>

// PNALayer: B=4, Nc=512, Nf=256, F_NHID=C_NHID=64, U_HID=U_OUT=128, M_INIT=1600, M_HID=256, M_OUT=64
// ALL I/O float32. R21 = R20 + (1) degF moved from prep1 (uncoalesced column reads) into prep2
// (coalesced row sweep), (2) mlp1 retiled 32x64/512thr/grid-256, (3) mlp2 2 rows/thread,
// (4) edge packed-f2 aggregation with full/boundary tile split.

using bs8 = __attribute__((ext_vector_type(8))) short;   // 8 bf16 in 4 VGPRs (MFMA A/B frag)
using f4  = __attribute__((ext_vector_type(4))) float;   // MFMA C/D frag
using f2  = __attribute__((ext_vector_type(2))) float;   // packed f32 pair (v_pk_* ops)

__device__ __forceinline__ unsigned short f2bf(float f) {
    union { float f; unsigned int u; } x; x.f = f;
    unsigned int u = x.u + 0x7FFFu + ((x.u >> 16) & 1u);
    return (unsigned short)(u >> 16);
}

// packed pair via v_cvt_pk_bf16_f32 (compiler emits it from the _rn intrinsic)
__device__ __forceinline__ unsigned int pkbf(float a, float b) {
    __hip_bfloat162 h = __float22bfloat162_rn(make_float2(a, b));
    union { __hip_bfloat162 h; unsigned int u; } c; c.h = h;
    return c.u;
}

// Stub-parity symbol (harmless).
__global__ void PNALayer_35081292874189_kernel() {}

// ---------------- workspace layout (bytes) ----------------
#define OFF_AC     0u          // 2048*128 f32 = 1048576
#define OFF_AF     1048576u    // 1024*128 f32 = 524288
#define OFF_DEGC   1572864u    // 2048 f32
#define OFF_DEGF   1581056u    // (unused now)
#define OFF_SCALE  1585152u    // 2048 f32
#define OFF_SINV   1593344u    // 2048 f32
#define OFF_FEATB  1601536u    // 2048*1600 bf16 = 6553600 (+256 slack for K-pad overread)
#define OFF_HMID   8155392u    // 2048*256 f32   = 2097152
#define OFF_W2T    10252544u   // 128*128 bf16   = 32768 (U_W2^T, n-major, bf16)
#define OFF_W1TB   10318080u   // 256*1664 bf16  = 851968 (M_W1^T, n-major, K zero-padded to 1664)
#define WS_NEED    11170048u

__global__ void PNALayer_ws_fail(float* out, int n) {
    int i = blockIdx.x * 256 + threadIdx.x;
    if (i < n) out[i] = 2500.0f;
}

// K1: A_c, A_f, degC, U_W2 transpose->bf16 (4 blocks), M_W1 transpose->bf16 (100 blocks), pad (1)
__global__ void PNALayer_prep1(
    const float* h_fac, const float* h_cus, const float* adj,
    const float* U_W1, const float* U_b1, const float* U_W2, const float* M_W1,
    float* wsAc, float* wsAf, float* wsDegC,
    unsigned short* wsW2Tb, unsigned short* wsW1Tb)
{
    __shared__ float sH[64];
    __shared__ float sRed[256];
    __shared__ float sT[64][65];
    int bid = blockIdx.x, t = threadIdx.x;

    if (bid < 1024) {
        int b = bid >> 8, f = bid & 255;
        if (t < 64) sH[t] = h_fac[(b * 256 + f) * 64 + t];
        __syncthreads();
        if (t < 128) {
            float acc = 0.f;
            for (int k = 0; k < 64; ++k)
                acc += sH[k] * U_W1[(64 + k) * 128 + t];
            wsAf[(b * 256 + f) * 128 + t] = acc;
        }
    } else if (bid < 3072) {
        int bc = bid - 1024;
        if (t < 64) sH[t] = h_cus[bc * 64 + t];
        __syncthreads();
        if (t < 128) {
            float acc = U_b1[t];
            for (int k = 0; k < 64; ++k)
                acc += sH[k] * U_W1[k * 128 + t];
            wsAc[bc * 128 + t] = acc;
        }
        float v = adj[bc * 256 + t];
        sRed[t] = v; __syncthreads();
        for (int s = 128; s > 0; s >>= 1) { if (t < s) sRed[t] += sRed[t + s]; __syncthreads(); }
        if (t == 0) wsDegC[bc] = sRed[0];
    } else if (bid < 3076) {
        // transpose U_W2 [k][n] -> wsW2Tb [n][k] bf16, 64x64 tiles
        int l = bid - 3072;
        int k0 = (l >> 1) * 64, n0 = (l & 1) * 64;
        for (int rep = 0; rep < 16; ++rep) {
            int idx = rep * 256 + t; int r = idx >> 6, c = idx & 63;
            sT[r][c] = U_W2[(k0 + r) * 128 + n0 + c];
        }
        __syncthreads();
        for (int rep = 0; rep < 16; ++rep) {
            int idx = rep * 256 + t; int r = idx >> 6, c = idx & 63;
            wsW2Tb[(n0 + r) * 128 + k0 + c] = f2bf(sT[c][r]);
        }
    } else if (bid < 3176) {
        // transpose M_W1 [k][n] (1600x256) -> wsW1Tb [n][k] bf16, 64x64 tiles
        int l = bid - 3076;            // 0..99
        int k0 = (l % 25) * 64, n0 = (l / 25) * 64;
        for (int rep = 0; rep < 16; ++rep) {
            int idx = rep * 256 + t; int r = idx >> 6, c = idx & 63;
            sT[r][c] = M_W1[(k0 + r) * 256 + n0 + c];
        }
        __syncthreads();
        for (int rep = 0; rep < 16; ++rep) {
            int idx = rep * 256 + t; int r = idx >> 6, c = idx & 63;
            wsW1Tb[(n0 + r) * 1664 + k0 + c] = f2bf(sT[c][r]);
        }
    } else {
        // zero the K-pad region k in [1600,1664) for all 256 n
        for (int i = 0; i < 64; ++i) {
            int idx = i * 256 + t;     // 0..16383
            int n = idx >> 6, k = 1600 + (idx & 63);
            wsW1Tb[n * 1664 + k] = 0;
        }
    }
}

// K2: degF (coalesced row sweep over adj), avg_d, scale, scale_inv per batch. Grid 4.
__global__ void PNALayer_prep2(
    const float* adj, const float* wsDegC, float* wsScale, float* wsSinv)
{
    __shared__ float sRed[256];
    __shared__ float sAvg;
    int b = blockIdx.x, t = threadIdx.x;
    // degF[t] for this batch: sum over 512 customers, coalesced (contiguous lanes)
    float df = 0.f;
    const float* ap = adj + b * 512 * 256 + t;
#pragma unroll 8
    for (int c = 0; c < 512; ++c)
        df += ap[c * 256];
    float v = logf(wsDegC[b * 512 + t] + 1.f) + logf(wsDegC[b * 512 + t + 256] + 1.f)
            + logf(df + 1.f);
    sRed[t] = v; __syncthreads();
    for (int s = 128; s > 0; s >>= 1) { if (t < s) sRed[t] += sRed[t + s]; __syncthreads(); }
    if (t == 0) sAvg = sRed[0] / 768.f;
    __syncthreads();
    float avg = sAvg;
    for (int c = t; c < 512; c += 256) {
        float lg = logf(wsDegC[b * 512 + c] + 1.f);
        float sc = lg / avg;
        float si = (sc != 0.f) ? 1.f / sc : 0.f;
        wsScale[b * 512 + c] = sc;
        wsSinv[b * 512 + c] = si;
    }
}

// K3: per-(b,c) edge MLP via MFMA + masked aggregation -> featB row (1600, bf16)
// 8 waves x 512 threads; wave w owns output cols [w*16, w*16+16).
// Mask compaction (ballot/popcount). Packed-f2 aggregation on full tiles; scalar
// bound-checked path only on the (single) boundary tile.
__global__ __launch_bounds__(512, 6) void PNALayer_edge(
    const float* h_cus, const float* edge, const float* adj,
    const float* U_W1, const float* U_b2,
    const float* wsAc, const float* wsAf, const unsigned short* wsW2Tb,
    const float* wsScale, const float* wsSinv,
    unsigned short* featB)
{
    __shared__ __align__(16) unsigned short sM1[64 * 136];
    __shared__ float sE[256];
    __shared__ float sAc[128];
    __shared__ float sWe[128];
    __shared__ unsigned short sFidx[256];
    __shared__ unsigned long long sBal[4];

    int bc = blockIdx.x;
    int b  = bc >> 9;
    int t  = threadIdx.x;
    int w = t >> 6, quad = (t >> 4) & 3, ln = t & 15;

    // B fragments for this wave's single 16-col tile, loaded once (global, L2-hit).
    int r0 = w * 16 + ln;
    bs8 bw[4];
#pragma unroll
    for (int kk = 0; kk < 4; ++kk)
        bw[kk] = *(const bs8*)(wsW2Tb + r0 * 128 + kk * 32 + quad * 8);
    float b2v = U_b2[r0];

    // Phase 1: masks + ballot, sE, sAc/sWe, h_cus featB slice
    bool m = false;
    unsigned long long bal = 0;
    if (t < 256) {
        sE[t] = edge[bc * 256 + t];
        m = adj[bc * 256 + t] > 0.f;
        bal = __ballot(m);
        if ((t & 63) == 0) sBal[t >> 6] = bal;
    }
    if (t >= 256 && t < 384) {
        int j = t - 256;
        sAc[j] = wsAc[bc * 128 + j];
        sWe[j] = U_W1[128 * 128 + j];
    }
    if (t >= 384 && t < 448) {
        int j = t - 384;
        featB[bc * 1600 + j] = f2bf(h_cus[bc * 64 + j]);
    }
    __syncthreads();

    // Phase 2: compacted facility index list
    unsigned long long b0 = sBal[0], b1 = sBal[1], b2 = sBal[2], b3 = sBal[3];
    int cnt = __popcll(b0) + __popcll(b1) + __popcll(b2) + __popcll(b3);
    if (t < 256) {
        int wv = t >> 6, l = t & 63;
        int base = 0;
        if (wv > 0) base += __popcll(b0);
        if (wv > 1) base += __popcll(b1);
        if (wv > 2) base += __popcll(b2);
        int rank = __popcll(bal & ((1ULL << l) - 1ULL));
        if (m) sFidx[base + rank] = (unsigned short)t;
    }
    __syncthreads();

    int ntiles = (cnt + 63) >> 6;

    f2 aS2  = (f2){0.f, 0.f},     aQ2  = (f2){0.f, 0.f};
    f2 aMx2 = (f2){-1e30f, -1e30f}, aMn2 = (f2){1e30f, 1e30f};
    const f2 zero2 = (f2){0.f, 0.f};

    for (int tl = 0; tl < ntiles; ++tl) {
        // stage: relu(A_c + A_f + e*We) -> bf16 sM1 (64 compacted edges x 128 dims)
#pragma unroll
        for (int i = 0; i < 4; ++i) {
            int idx = i * 512 + t;
            int fl = idx >> 5, k = (idx & 31) * 4;
            int fj = tl * 64 + fl;
            uint2 p = make_uint2(0u, 0u);
            if (fj < cnt) {
                int f = sFidx[fj];
                float4 af  = *(const float4*)(wsAf + (b * 256 + f) * 128 + k);
                f2 ac01 = *(const f2*)(sAc + k);
                f2 ac23 = *(const f2*)(sAc + k + 2);
                f2 we01 = *(const f2*)(sWe + k);
                f2 we23 = *(const f2*)(sWe + k + 2);
                float e = sE[f];
                f2 e2 = (f2){e, e};
                f2 s01 = ac01 + (f2){af.x, af.y};
                f2 s23 = ac23 + (f2){af.z, af.w};
                s01 = __builtin_elementwise_fma(e2, we01, s01);
                s23 = __builtin_elementwise_fma(e2, we23, s23);
                f2 r01 = __builtin_elementwise_max(s01, zero2);
                f2 r23 = __builtin_elementwise_max(s23, zero2);
                p.x = pkbf(r01.x, r01.y);
                p.y = pkbf(r23.x, r23.y);
            }
            *(uint2*)(sM1 + fl * 136 + k) = p;
        }
        __syncthreads();

        f4 acc[4];
#pragma unroll
        for (int rt = 0; rt < 4; ++rt) acc[rt] = (f4){0.f, 0.f, 0.f, 0.f};
#pragma unroll
        for (int kk = 0; kk < 4; ++kk) {
            int ko = kk * 32 + quad * 8;
#pragma unroll
            for (int rt = 0; rt < 4; ++rt) {
                bs8 a = *(const bs8*)(sM1 + (rt * 16 + ln) * 136 + ko);
                acc[rt] = __builtin_amdgcn_mfma_f32_16x16x32_bf16(a, bw[kk], acc[rt], 0, 0, 0);
            }
        }

        if (((tl + 1) << 6) <= cnt) {
            // full tile: packed-f2 aggregation, no bound checks (2 elems/inst)
#pragma unroll
            for (int rt = 0; rt < 4; ++rt) {
                f2 p01 = (f2){acc[rt][0], acc[rt][1]};
                f2 p23 = (f2){acc[rt][2], acc[rt][3]};
                aS2 = aS2 + p01;
                aS2 = aS2 + p23;
                aQ2 = __builtin_elementwise_fma(p01, p01, aQ2);
                aQ2 = __builtin_elementwise_fma(p23, p23, aQ2);
                f2 mx = __builtin_elementwise_max(p01, p23);
                f2 mn = __builtin_elementwise_min(p01, p23);
                aMx2 = __builtin_elementwise_max(aMx2, mx);
                aMn2 = __builtin_elementwise_min(aMn2, mn);
            }
        } else {
            // boundary tile: scalar with bound check
#pragma unroll
            for (int rt = 0; rt < 4; ++rt) {
#pragma unroll
                for (int i = 0; i < 4; ++i) {
                    int fj = tl * 64 + rt * 16 + quad * 4 + i;
                    if (fj < cnt) {
                        float v = acc[rt][i];
                        aS2.x += v;
                        aQ2.x = fmaf(v, v, aQ2.x);
                        aMx2.x = fmaxf(aMx2.x, v);
                        aMn2.x = fminf(aMn2.x, v);
                    }
                }
            }
        }
        __syncthreads();
    }

    float aS = aS2.x + aS2.y;
    float aQ = aQ2.x + aQ2.y;
    float aMx = fmaxf(aMx2.x, aMx2.y);
    float aMn = fminf(aMn2.x, aMn2.y);

    // finish reduction across the 4 quads (rows live on lanes quad*16+ln)
    aS  += __shfl_xor(aS, 16, 64);  aS  += __shfl_xor(aS, 32, 64);
    aQ  += __shfl_xor(aQ, 16, 64);  aQ  += __shfl_xor(aQ, 32, 64);
    aMx = fmaxf(aMx, __shfl_xor(aMx, 16, 64));
    aMx = fmaxf(aMx, __shfl_xor(aMx, 32, 64));
    aMn = fminf(aMn, __shfl_xor(aMn, 16, 64));
    aMn = fminf(aMn, __shfl_xor(aMn, 32, 64));

    if (quad == 0) {
        float cntf = (float)cnt;
        float sc = wsScale[bc], si = wsSinv[bc];
        unsigned short* fr = featB + bc * 1600;
        int col = w * 16 + ln;
        float meanr = aS / cntf;
        float mean  = meanr + b2v;                           // bias shift
        float var   = fmaxf(aQ / cntf - meanr * meanr, 0.f); // bias-invariant
        float stdv  = sqrtf(var);
        float mx = aMx + b2v, mn = aMn + b2v;
        fr[64 + col]   = f2bf(mean); fr[192 + col]  = f2bf(mean * sc); fr[320 + col]  = f2bf(mean * si);
        fr[448 + col]  = f2bf(stdv); fr[576 + col]  = f2bf(stdv * sc); fr[704 + col]  = f2bf(stdv * si);
        fr[832 + col]  = f2bf(mx);   fr[960 + col]  = f2bf(mx * sc);   fr[1088 + col] = f2bf(mx * si);
        fr[1216 + col] = f2bf(mn);   fr[1344 + col] = f2bf(mn * sc);   fr[1472 + col] = f2bf(mn * si);
    }
}

// K4: h_mid = relu(featB @ W1Tb^T + b1) via MFMA. Block = 32 rows x 64 cols, 512 thr, grid 256.
// 8 waves in 2x4 grid of 16x16 tiles. Stage-loads per thread per ktile: 3 uint4 (was 5 for 4 MFMA).
// LDS: sA bf16[32][136]=8704B, sB bf16[64][136]=17408B  (26112 B total)
__global__ __launch_bounds__(512, 2) void PNALayer_mlp1(
    const unsigned short* featB, const unsigned short* wsW1Tb, const float* M_b1,
    float* h_mid)
{
    __shared__ __align__(16) unsigned short sA[32 * 136];
    __shared__ __align__(16) unsigned short sB[64 * 136];
    int t = threadIdx.x;
    int rb = (blockIdx.x >> 2) * 32, cb = (blockIdx.x & 3) * 64;
    int w = t >> 6, quad = (t >> 4) & 3, ln = t & 15;
    int wr = w >> 2, wc = w & 3;   // wave tile: rows [wr*16,+16), cols [wc*16,+16)

    f4 acc = (f4){0.f, 0.f, 0.f, 0.f};

    for (int kt = 0; kt < 13; ++kt) {
        int kb = kt * 128;
        {   // stage A: 32 rows x 128 k (512 uint4, 1/thread)
            int row = t >> 4, c8 = (t & 15) * 8;
            *(uint4*)(sA + row * 136 + c8) =
                *(const uint4*)(featB + (rb + row) * 1600 + kb + c8);
        }
#pragma unroll
        for (int i = 0; i < 2; ++i) {   // stage B: 64 n-rows x 128 k (1024 uint4, 2/thread)
            int vi = i * 512 + t;
            int row = vi >> 4, c8 = (vi & 15) * 8;
            *(uint4*)(sB + row * 136 + c8) =
                *(const uint4*)(wsW1Tb + (cb + row) * 1664 + kb + c8);
        }
        __syncthreads();
#pragma unroll
        for (int kk = 0; kk < 4; ++kk) {
            int ko = kk * 32 + quad * 8;
            bs8 a  = *(const bs8*)(sA + (wr * 16 + ln) * 136 + ko);
            bs8 bb = *(const bs8*)(sB + (wc * 16 + ln) * 136 + ko);
            acc = __builtin_amdgcn_mfma_f32_16x16x32_bf16(a, bb, acc, 0, 0, 0);
        }
        __syncthreads();
    }
    // C/D: col=ln (n), row=quad*4+i (m)
    int col = cb + wc * 16 + ln;
    float b1v = M_b1[col];
#pragma unroll
    for (int i = 0; i < 4; ++i) {
        int row = rb + wr * 16 + quad * 4 + i;
        h_mid[row * 256 + col] = fmaxf(acc[i] + b1v, 0.f);
    }
}

// K5: out = h_mid @ M_W2 + b2  (f32). 2 rows/thread share each M_W2 load. Grid 256.
__global__ void PNALayer_mlp2(
    const float* h_mid, const float* M_W2, const float* M_b2, float* out)
{
    int q = blockIdx.x * 256 + threadIdx.x;   // [0, 65536)
    int row0 = q >> 6, j = q & 63;
    int row1 = row0 + 1024;
    float acc0 = M_b2[j], acc1 = acc0;
    const float* h0 = h_mid + row0 * 256;
    const float* h1 = h_mid + row1 * 256;
#pragma unroll 8
    for (int k = 0; k < 256; ++k) {
        float wv = M_W2[k * 64 + j];
        acc0 = fmaf(h0[k], wv, acc0);
        acc1 = fmaf(h1[k], wv, acc1);
    }
    out[row0 * 64 + j] = acc0;
    out[row1 * 64 + j] = acc1;
}

extern "C" void kernel_launch(void* const* d_in, const int* in_sizes, int n_in,
                              void* d_out, int out_size, void* d_ws, size_t ws_size,
                              hipStream_t stream) {
    const float* h_fac = (const float*)d_in[0];
    const float* h_cus = (const float*)d_in[1];
    const float* edge  = (const float*)d_in[2];
    const float* adj   = (const float*)d_in[3];
    const float* U_W1  = (const float*)d_in[4];
    const float* U_b1  = (const float*)d_in[5];
    const float* U_W2  = (const float*)d_in[6];
    const float* U_b2  = (const float*)d_in[7];
    const float* M_W1  = (const float*)d_in[8];
    const float* M_b1  = (const float*)d_in[9];
    const float* M_W2  = (const float*)d_in[10];
    const float* M_b2  = (const float*)d_in[11];
    (void)in_sizes; (void)n_in;

    float* outp = (float*)d_out;
    int nblk_out = (out_size + 255) / 256;

    if (ws_size < (size_t)WS_NEED) {
        PNALayer_ws_fail<<<nblk_out, 256, 0, stream>>>(outp, out_size);
        return;
    }

    char* ws = (char*)d_ws;
    float*          wsAc   = (float*)(ws + OFF_AC);
    float*          wsAf   = (float*)(ws + OFF_AF);
    float*          wsDegC = (float*)(ws + OFF_DEGC);
    float*          wsScal = (float*)(ws + OFF_SCALE);
    float*          wsSinv = (float*)(ws + OFF_SINV);
    unsigned short* wsFeatB= (unsigned short*)(ws + OFF_FEATB);
    float*          wsHmid = (float*)(ws + OFF_HMID);
    unsigned short* wsW2Tb = (unsigned short*)(ws + OFF_W2T);
    unsigned short* wsW1Tb = (unsigned short*)(ws + OFF_W1TB);

    PNALayer_prep1<<<3177, 256, 0, stream>>>(
        h_fac, h_cus, adj, U_W1, U_b1, U_W2, M_W1,
        wsAc, wsAf, wsDegC, wsW2Tb, wsW1Tb);
    PNALayer_prep2<<<4, 256, 0, stream>>>(adj, wsDegC, wsScal, wsSinv);
    PNALayer_edge<<<2048, 512, 0, stream>>>(
        h_cus, edge, adj, U_W1, U_b2,
        wsAc, wsAf, wsW2Tb, wsScal, wsSinv, wsFeatB);
    PNALayer_mlp1<<<256, 512, 0, stream>>>(wsFeatB, wsW1Tb, M_b1, wsHmid);
    PNALayer_mlp2<<<256, 256, 0, stream>>>(wsHmid, M_W2, M_b2, outp);
}

// Round 5
// 146.343 us; speedup vs baseline: 1.1271x; 1.1271x over previous
//
#include <hip/hip_runtime.h>
#include <hip/hip_bf16.h>

// PNALayer: B=4, Nc=512, Nf=256, F_NHID=C_NHID=64, U_HID=U_OUT=128, M_INIT=1600, M_HID=256, M_OUT=64
// ALL I/O float32. R22 = R21 + degF fix: 64 coalesced partial-sum blocks appended to prep1
// (4 batches x 16 chunks of 32 customer rows), prep2 reduces the 16 partials (was: grid-4
// serial sweep of 2MB adj = ~25us serialization bug).

using bs8 = __attribute__((ext_vector_type(8))) short;   // 8 bf16 in 4 VGPRs (MFMA A/B frag)
using f4  = __attribute__((ext_vector_type(4))) float;   // MFMA C/D frag
using f2  = __attribute__((ext_vector_type(2))) float;   // packed f32 pair (v_pk_* ops)

__device__ __forceinline__ unsigned short f2bf(float f) {
    union { float f; unsigned int u; } x; x.f = f;
    unsigned int u = x.u + 0x7FFFu + ((x.u >> 16) & 1u);
    return (unsigned short)(u >> 16);
}

// packed pair via v_cvt_pk_bf16_f32 (compiler emits it from the _rn intrinsic)
__device__ __forceinline__ unsigned int pkbf(float a, float b) {
    __hip_bfloat162 h = __float22bfloat162_rn(make_float2(a, b));
    union { __hip_bfloat162 h; unsigned int u; } c; c.h = h;
    return c.u;
}

// Stub-parity symbol (harmless).
__global__ void PNALayer_35081292874189_kernel() {}

// ---------------- workspace layout (bytes) ----------------
#define OFF_AC     0u          // 2048*128 f32 = 1048576
#define OFF_AF     1048576u    // 1024*128 f32 = 524288
#define OFF_DEGC   1572864u    // 2048 f32
#define OFF_SCALE  1585152u    // 2048 f32
#define OFF_SINV   1593344u    // 2048 f32
#define OFF_FEATB  1601536u    // 2048*1600 bf16 = 6553600 (+256 slack for K-pad overread)
#define OFF_HMID   8155392u    // 2048*256 f32   = 2097152
#define OFF_W2T    10252544u   // 128*128 bf16   = 32768 (U_W2^T, n-major, bf16)
#define OFF_W1TB   10318080u   // 256*1664 bf16  = 851968 (M_W1^T, n-major, K zero-padded to 1664)
#define OFF_DEGFP  11170048u   // 4*16*256 f32   = 65536 (degF partials: [b][chunk][f])
#define WS_NEED    11235584u

__global__ void PNALayer_ws_fail(float* out, int n) {
    int i = blockIdx.x * 256 + threadIdx.x;
    if (i < n) out[i] = 2500.0f;
}

// K1: A_c, A_f, degC, U_W2 transpose->bf16 (4), M_W1 transpose->bf16 (100), pad (1),
//     degF partials (64: 4 batches x 16 chunks of 32 customer rows, coalesced).
__global__ void PNALayer_prep1(
    const float* h_fac, const float* h_cus, const float* adj,
    const float* U_W1, const float* U_b1, const float* U_W2, const float* M_W1,
    float* wsAc, float* wsAf, float* wsDegC,
    unsigned short* wsW2Tb, unsigned short* wsW1Tb, float* wsDegFP)
{
    __shared__ float sH[64];
    __shared__ float sRed[256];
    __shared__ float sT[64][65];
    int bid = blockIdx.x, t = threadIdx.x;

    if (bid < 1024) {
        int b = bid >> 8, f = bid & 255;
        if (t < 64) sH[t] = h_fac[(b * 256 + f) * 64 + t];
        __syncthreads();
        if (t < 128) {
            float acc = 0.f;
            for (int k = 0; k < 64; ++k)
                acc += sH[k] * U_W1[(64 + k) * 128 + t];
            wsAf[(b * 256 + f) * 128 + t] = acc;
        }
    } else if (bid < 3072) {
        int bc = bid - 1024;
        if (t < 64) sH[t] = h_cus[bc * 64 + t];
        __syncthreads();
        if (t < 128) {
            float acc = U_b1[t];
            for (int k = 0; k < 64; ++k)
                acc += sH[k] * U_W1[k * 128 + t];
            wsAc[bc * 128 + t] = acc;
        }
        float v = adj[bc * 256 + t];
        sRed[t] = v; __syncthreads();
        for (int s = 128; s > 0; s >>= 1) { if (t < s) sRed[t] += sRed[t + s]; __syncthreads(); }
        if (t == 0) wsDegC[bc] = sRed[0];
    } else if (bid < 3076) {
        // transpose U_W2 [k][n] -> wsW2Tb [n][k] bf16, 64x64 tiles
        int l = bid - 3072;
        int k0 = (l >> 1) * 64, n0 = (l & 1) * 64;
        for (int rep = 0; rep < 16; ++rep) {
            int idx = rep * 256 + t; int r = idx >> 6, c = idx & 63;
            sT[r][c] = U_W2[(k0 + r) * 128 + n0 + c];
        }
        __syncthreads();
        for (int rep = 0; rep < 16; ++rep) {
            int idx = rep * 256 + t; int r = idx >> 6, c = idx & 63;
            wsW2Tb[(n0 + r) * 128 + k0 + c] = f2bf(sT[c][r]);
        }
    } else if (bid < 3176) {
        // transpose M_W1 [k][n] (1600x256) -> wsW1Tb [n][k] bf16, 64x64 tiles
        int l = bid - 3076;            // 0..99
        int k0 = (l % 25) * 64, n0 = (l / 25) * 64;
        for (int rep = 0; rep < 16; ++rep) {
            int idx = rep * 256 + t; int r = idx >> 6, c = idx & 63;
            sT[r][c] = M_W1[(k0 + r) * 256 + n0 + c];
        }
        __syncthreads();
        for (int rep = 0; rep < 16; ++rep) {
            int idx = rep * 256 + t; int r = idx >> 6, c = idx & 63;
            wsW1Tb[(n0 + r) * 1664 + k0 + c] = f2bf(sT[c][r]);
        }
    } else if (bid < 3177) {
        // zero the K-pad region k in [1600,1664) for all 256 n
        for (int i = 0; i < 64; ++i) {
            int idx = i * 256 + t;     // 0..16383
            int n = idx >> 6, k = 1600 + (idx & 63);
            wsW1Tb[n * 1664 + k] = 0;
        }
    } else {
        // degF partials: block (b, chunk) sums 32 customer rows, coalesced lanes over f
        int l = bid - 3177;            // 0..63
        int b = l >> 4, ch = l & 15;
        const float* ap = adj + (b * 512 + ch * 32) * 256 + t;
        float s = 0.f;
#pragma unroll 8
        for (int c = 0; c < 32; ++c)
            s += ap[c * 256];
        wsDegFP[(b * 16 + ch) * 256 + t] = s;
    }
}

// K2: degF from 16 partials, avg_d, scale, scale_inv per batch. Grid 4.
__global__ void PNALayer_prep2(
    const float* wsDegFP, const float* wsDegC, float* wsScale, float* wsSinv)
{
    __shared__ float sRed[256];
    __shared__ float sAvg;
    int b = blockIdx.x, t = threadIdx.x;
    float df = 0.f;
#pragma unroll
    for (int ch = 0; ch < 16; ++ch)
        df += wsDegFP[(b * 16 + ch) * 256 + t];
    float v = logf(wsDegC[b * 512 + t] + 1.f) + logf(wsDegC[b * 512 + t + 256] + 1.f)
            + logf(df + 1.f);
    sRed[t] = v; __syncthreads();
    for (int s = 128; s > 0; s >>= 1) { if (t < s) sRed[t] += sRed[t + s]; __syncthreads(); }
    if (t == 0) sAvg = sRed[0] / 768.f;
    __syncthreads();
    float avg = sAvg;
    for (int c = t; c < 512; c += 256) {
        float lg = logf(wsDegC[b * 512 + c] + 1.f);
        float sc = lg / avg;
        float si = (sc != 0.f) ? 1.f / sc : 0.f;
        wsScale[b * 512 + c] = sc;
        wsSinv[b * 512 + c] = si;
    }
}

// K3: per-(b,c) edge MLP via MFMA + masked aggregation -> featB row (1600, bf16)
// 8 waves x 512 threads; wave w owns output cols [w*16, w*16+16).
// Mask compaction (ballot/popcount). Packed-f2 aggregation on full tiles; scalar
// bound-checked path only on the (single) boundary tile.
__global__ __launch_bounds__(512, 6) void PNALayer_edge(
    const float* h_cus, const float* edge, const float* adj,
    const float* U_W1, const float* U_b2,
    const float* wsAc, const float* wsAf, const unsigned short* wsW2Tb,
    const float* wsScale, const float* wsSinv,
    unsigned short* featB)
{
    __shared__ __align__(16) unsigned short sM1[64 * 136];
    __shared__ float sE[256];
    __shared__ float sAc[128];
    __shared__ float sWe[128];
    __shared__ unsigned short sFidx[256];
    __shared__ unsigned long long sBal[4];

    int bc = blockIdx.x;
    int b  = bc >> 9;
    int t  = threadIdx.x;
    int w = t >> 6, quad = (t >> 4) & 3, ln = t & 15;

    // B fragments for this wave's single 16-col tile, loaded once (global, L2-hit).
    int r0 = w * 16 + ln;
    bs8 bw[4];
#pragma unroll
    for (int kk = 0; kk < 4; ++kk)
        bw[kk] = *(const bs8*)(wsW2Tb + r0 * 128 + kk * 32 + quad * 8);
    float b2v = U_b2[r0];

    // Phase 1: masks + ballot, sE, sAc/sWe, h_cus featB slice
    bool m = false;
    unsigned long long bal = 0;
    if (t < 256) {
        sE[t] = edge[bc * 256 + t];
        m = adj[bc * 256 + t] > 0.f;
        bal = __ballot(m);
        if ((t & 63) == 0) sBal[t >> 6] = bal;
    }
    if (t >= 256 && t < 384) {
        int j = t - 256;
        sAc[j] = wsAc[bc * 128 + j];
        sWe[j] = U_W1[128 * 128 + j];
    }
    if (t >= 384 && t < 448) {
        int j = t - 384;
        featB[bc * 1600 + j] = f2bf(h_cus[bc * 64 + j]);
    }
    __syncthreads();

    // Phase 2: compacted facility index list
    unsigned long long b0 = sBal[0], b1 = sBal[1], b2 = sBal[2], b3 = sBal[3];
    int cnt = __popcll(b0) + __popcll(b1) + __popcll(b2) + __popcll(b3);
    if (t < 256) {
        int wv = t >> 6, l = t & 63;
        int base = 0;
        if (wv > 0) base += __popcll(b0);
        if (wv > 1) base += __popcll(b1);
        if (wv > 2) base += __popcll(b2);
        int rank = __popcll(bal & ((1ULL << l) - 1ULL));
        if (m) sFidx[base + rank] = (unsigned short)t;
    }
    __syncthreads();

    int ntiles = (cnt + 63) >> 6;

    f2 aS2  = (f2){0.f, 0.f},     aQ2  = (f2){0.f, 0.f};
    f2 aMx2 = (f2){-1e30f, -1e30f}, aMn2 = (f2){1e30f, 1e30f};
    const f2 zero2 = (f2){0.f, 0.f};

    for (int tl = 0; tl < ntiles; ++tl) {
        // stage: relu(A_c + A_f + e*We) -> bf16 sM1 (64 compacted edges x 128 dims)
#pragma unroll
        for (int i = 0; i < 4; ++i) {
            int idx = i * 512 + t;
            int fl = idx >> 5, k = (idx & 31) * 4;
            int fj = tl * 64 + fl;
            uint2 p = make_uint2(0u, 0u);
            if (fj < cnt) {
                int f = sFidx[fj];
                float4 af  = *(const float4*)(wsAf + (b * 256 + f) * 128 + k);
                f2 ac01 = *(const f2*)(sAc + k);
                f2 ac23 = *(const f2*)(sAc + k + 2);
                f2 we01 = *(const f2*)(sWe + k);
                f2 we23 = *(const f2*)(sWe + k + 2);
                float e = sE[f];
                f2 e2 = (f2){e, e};
                f2 s01 = ac01 + (f2){af.x, af.y};
                f2 s23 = ac23 + (f2){af.z, af.w};
                s01 = __builtin_elementwise_fma(e2, we01, s01);
                s23 = __builtin_elementwise_fma(e2, we23, s23);
                f2 r01 = __builtin_elementwise_max(s01, zero2);
                f2 r23 = __builtin_elementwise_max(s23, zero2);
                p.x = pkbf(r01.x, r01.y);
                p.y = pkbf(r23.x, r23.y);
            }
            *(uint2*)(sM1 + fl * 136 + k) = p;
        }
        __syncthreads();

        f4 acc[4];
#pragma unroll
        for (int rt = 0; rt < 4; ++rt) acc[rt] = (f4){0.f, 0.f, 0.f, 0.f};
#pragma unroll
        for (int kk = 0; kk < 4; ++kk) {
            int ko = kk * 32 + quad * 8;
#pragma unroll
            for (int rt = 0; rt < 4; ++rt) {
                bs8 a = *(const bs8*)(sM1 + (rt * 16 + ln) * 136 + ko);
                acc[rt] = __builtin_amdgcn_mfma_f32_16x16x32_bf16(a, bw[kk], acc[rt], 0, 0, 0);
            }
        }

        if (((tl + 1) << 6) <= cnt) {
            // full tile: packed-f2 aggregation, no bound checks (2 elems/inst)
#pragma unroll
            for (int rt = 0; rt < 4; ++rt) {
                f2 p01 = (f2){acc[rt][0], acc[rt][1]};
                f2 p23 = (f2){acc[rt][2], acc[rt][3]};
                aS2 = aS2 + p01;
                aS2 = aS2 + p23;
                aQ2 = __builtin_elementwise_fma(p01, p01, aQ2);
                aQ2 = __builtin_elementwise_fma(p23, p23, aQ2);
                f2 mx = __builtin_elementwise_max(p01, p23);
                f2 mn = __builtin_elementwise_min(p01, p23);
                aMx2 = __builtin_elementwise_max(aMx2, mx);
                aMn2 = __builtin_elementwise_min(aMn2, mn);
            }
        } else {
            // boundary tile: scalar with bound check
#pragma unroll
            for (int rt = 0; rt < 4; ++rt) {
#pragma unroll
                for (int i = 0; i < 4; ++i) {
                    int fj = tl * 64 + rt * 16 + quad * 4 + i;
                    if (fj < cnt) {
                        float v = acc[rt][i];
                        aS2.x += v;
                        aQ2.x = fmaf(v, v, aQ2.x);
                        aMx2.x = fmaxf(aMx2.x, v);
                        aMn2.x = fminf(aMn2.x, v);
                    }
                }
            }
        }
        __syncthreads();
    }

    float aS = aS2.x + aS2.y;
    float aQ = aQ2.x + aQ2.y;
    float aMx = fmaxf(aMx2.x, aMx2.y);
    float aMn = fminf(aMn2.x, aMn2.y);

    // finish reduction across the 4 quads (rows live on lanes quad*16+ln)
    aS  += __shfl_xor(aS, 16, 64);  aS  += __shfl_xor(aS, 32, 64);
    aQ  += __shfl_xor(aQ, 16, 64);  aQ  += __shfl_xor(aQ, 32, 64);
    aMx = fmaxf(aMx, __shfl_xor(aMx, 16, 64));
    aMx = fmaxf(aMx, __shfl_xor(aMx, 32, 64));
    aMn = fminf(aMn, __shfl_xor(aMn, 16, 64));
    aMn = fminf(aMn, __shfl_xor(aMn, 32, 64));

    if (quad == 0) {
        float cntf = (float)cnt;
        float sc = wsScale[bc], si = wsSinv[bc];
        unsigned short* fr = featB + bc * 1600;
        int col = w * 16 + ln;
        float meanr = aS / cntf;
        float mean  = meanr + b2v;                           // bias shift
        float var   = fmaxf(aQ / cntf - meanr * meanr, 0.f); // bias-invariant
        float stdv  = sqrtf(var);
        float mx = aMx + b2v, mn = aMn + b2v;
        fr[64 + col]   = f2bf(mean); fr[192 + col]  = f2bf(mean * sc); fr[320 + col]  = f2bf(mean * si);
        fr[448 + col]  = f2bf(stdv); fr[576 + col]  = f2bf(stdv * sc); fr[704 + col]  = f2bf(stdv * si);
        fr[832 + col]  = f2bf(mx);   fr[960 + col]  = f2bf(mx * sc);   fr[1088 + col] = f2bf(mx * si);
        fr[1216 + col] = f2bf(mn);   fr[1344 + col] = f2bf(mn * sc);   fr[1472 + col] = f2bf(mn * si);
    }
}

// K4: h_mid = relu(featB @ W1Tb^T + b1) via MFMA. Block = 32 rows x 64 cols, 512 thr, grid 256.
// 8 waves in 2x4 grid of 16x16 tiles. Stage-loads per thread per ktile: 3 uint4.
// LDS: sA bf16[32][136]=8704B, sB bf16[64][136]=17408B  (26112 B total)
__global__ __launch_bounds__(512, 2) void PNALayer_mlp1(
    const unsigned short* featB, const unsigned short* wsW1Tb, const float* M_b1,
    float* h_mid)
{
    __shared__ __align__(16) unsigned short sA[32 * 136];
    __shared__ __align__(16) unsigned short sB[64 * 136];
    int t = threadIdx.x;
    int rb = (blockIdx.x >> 2) * 32, cb = (blockIdx.x & 3) * 64;
    int w = t >> 6, quad = (t >> 4) & 3, ln = t & 15;
    int wr = w >> 2, wc = w & 3;   // wave tile: rows [wr*16,+16), cols [wc*16,+16)

    f4 acc = (f4){0.f, 0.f, 0.f, 0.f};

    for (int kt = 0; kt < 13; ++kt) {
        int kb = kt * 128;
        {   // stage A: 32 rows x 128 k (512 uint4, 1/thread)
            int row = t >> 4, c8 = (t & 15) * 8;
            *(uint4*)(sA + row * 136 + c8) =
                *(const uint4*)(featB + (rb + row) * 1600 + kb + c8);
        }
#pragma unroll
        for (int i = 0; i < 2; ++i) {   // stage B: 64 n-rows x 128 k (1024 uint4, 2/thread)
            int vi = i * 512 + t;
            int row = vi >> 4, c8 = (vi & 15) * 8;
            *(uint4*)(sB + row * 136 + c8) =
                *(const uint4*)(wsW1Tb + (cb + row) * 1664 + kb + c8);
        }
        __syncthreads();
#pragma unroll
        for (int kk = 0; kk < 4; ++kk) {
            int ko = kk * 32 + quad * 8;
            bs8 a  = *(const bs8*)(sA + (wr * 16 + ln) * 136 + ko);
            bs8 bb = *(const bs8*)(sB + (wc * 16 + ln) * 136 + ko);
            acc = __builtin_amdgcn_mfma_f32_16x16x32_bf16(a, bb, acc, 0, 0, 0);
        }
        __syncthreads();
    }
    // C/D: col=ln (n), row=quad*4+i (m)
    int col = cb + wc * 16 + ln;
    float b1v = M_b1[col];
#pragma unroll
    for (int i = 0; i < 4; ++i) {
        int row = rb + wr * 16 + quad * 4 + i;
        h_mid[row * 256 + col] = fmaxf(acc[i] + b1v, 0.f);
    }
}

// K5: out = h_mid @ M_W2 + b2  (f32). 2 rows/thread share each M_W2 load. Grid 256.
__global__ void PNALayer_mlp2(
    const float* h_mid, const float* M_W2, const float* M_b2, float* out)
{
    int q = blockIdx.x * 256 + threadIdx.x;   // [0, 65536)
    int row0 = q >> 6, j = q & 63;
    int row1 = row0 + 1024;
    float acc0 = M_b2[j], acc1 = acc0;
    const float* h0 = h_mid + row0 * 256;
    const float* h1 = h_mid + row1 * 256;
#pragma unroll 8
    for (int k = 0; k < 256; ++k) {
        float wv = M_W2[k * 64 + j];
        acc0 = fmaf(h0[k], wv, acc0);
        acc1 = fmaf(h1[k], wv, acc1);
    }
    out[row0 * 64 + j] = acc0;
    out[row1 * 64 + j] = acc1;
}

extern "C" void kernel_launch(void* const* d_in, const int* in_sizes, int n_in,
                              void* d_out, int out_size, void* d_ws, size_t ws_size,
                              hipStream_t stream) {
    const float* h_fac = (const float*)d_in[0];
    const float* h_cus = (const float*)d_in[1];
    const float* edge  = (const float*)d_in[2];
    const float* adj   = (const float*)d_in[3];
    const float* U_W1  = (const float*)d_in[4];
    const float* U_b1  = (const float*)d_in[5];
    const float* U_W2  = (const float*)d_in[6];
    const float* U_b2  = (const float*)d_in[7];
    const float* M_W1  = (const float*)d_in[8];
    const float* M_b1  = (const float*)d_in[9];
    const float* M_W2  = (const float*)d_in[10];
    const float* M_b2  = (const float*)d_in[11];
    (void)in_sizes; (void)n_in;

    float* outp = (float*)d_out;
    int nblk_out = (out_size + 255) / 256;

    if (ws_size < (size_t)WS_NEED) {
        PNALayer_ws_fail<<<nblk_out, 256, 0, stream>>>(outp, out_size);
        return;
    }

    char* ws = (char*)d_ws;
    float*          wsAc   = (float*)(ws + OFF_AC);
    float*          wsAf   = (float*)(ws + OFF_AF);
    float*          wsDegC = (float*)(ws + OFF_DEGC);
    float*          wsScal = (float*)(ws + OFF_SCALE);
    float*          wsSinv = (float*)(ws + OFF_SINV);
    unsigned short* wsFeatB= (unsigned short*)(ws + OFF_FEATB);
    float*          wsHmid = (float*)(ws + OFF_HMID);
    unsigned short* wsW2Tb = (unsigned short*)(ws + OFF_W2T);
    unsigned short* wsW1Tb = (unsigned short*)(ws + OFF_W1TB);
    float*          wsDegFP= (float*)(ws + OFF_DEGFP);

    PNALayer_prep1<<<3241, 256, 0, stream>>>(
        h_fac, h_cus, adj, U_W1, U_b1, U_W2, M_W1,
        wsAc, wsAf, wsDegC, wsW2Tb, wsW1Tb, wsDegFP);
    PNALayer_prep2<<<4, 256, 0, stream>>>(wsDegFP, wsDegC, wsScal, wsSinv);
    PNALayer_edge<<<2048, 512, 0, stream>>>(
        h_cus, edge, adj, U_W1, U_b2,
        wsAc, wsAf, wsW2Tb, wsScal, wsSinv, wsFeatB);
    PNALayer_mlp1<<<256, 512, 0, stream>>>(wsFeatB, wsW1Tb, M_b1, wsHmid);
    PNALayer_mlp2<<<256, 256, 0, stream>>>(wsHmid, M_W2, M_b2, outp);
}